// Round 2
// baseline (301.210 us; speedup 1.0000x reference)
//
#include <hip/hip_runtime.h>
#include <math.h>

// Problem constants
#define BB 32
#define CC 21
#define TT 512
#define LL 336
#define FREQ 257            // TT/2 + 1
#define NBC (BB*CC)         // 672
#define WROW (FREQ*TT)      // 131584 floats per head_w row

#define ANG (6.2831853071795864769e0f / 512.0f)   // 2*pi/T

__device__ __forceinline__ float wave_sum(float v) {
#pragma unroll
    for (int off = 32; off; off >>= 1) v += __shfl_xor(v, off);
    return v;
}

// ---------------------------------------------------------------------------
// kA: fused per-(b,c) stats + DFT of raw z rows.
//   ZC[bc,p] = sum_t z_t cos(2pi p t/T),  ZS[bc,p] = sum_t z_t sin(2pi p t/T)
// Even/odd fold halves the t-loop (cos/sin(theta+pi*p) = (-1)^p ...).
// Exact trig via per-block LDS table (cospif/sinpif), idx = (p*t) & 511.
// grid = 672 blocks x 320 threads (p = tid for tid < 257).
// ---------------------------------------------------------------------------
__global__ __launch_bounds__(320) void kA_zdft(const float* __restrict__ z,
                                               const float* __restrict__ aw,
                                               const float* __restrict__ ab,
                                               float* __restrict__ ZC,
                                               float* __restrict__ ZS,
                                               float* __restrict__ stats) {
    __shared__ float  zrow[512];
    __shared__ float  zeo[512];     // [0,256) even fold, [256,512) odd fold
    __shared__ float2 tab[512];     // (cos, sin)(2*pi*k/512), exact
    __shared__ float  red[10];
    const int bc  = blockIdx.x;
    const int tid = threadIdx.x;
    const float* zr = z + (size_t)bc * TT;

    float v0 = zr[tid];
    float v1 = (tid < 192) ? zr[tid + 320] : 0.0f;
    zrow[tid] = v0;
    if (tid < 192) zrow[tid + 320] = v1;

    float s  = v0 + v1;
    float sq = v0 * v0 + v1 * v1;
    s  = wave_sum(s);
    sq = wave_sum(sq);
    const int lane = tid & 63, wv = tid >> 6;
    if (lane == 0) { red[wv] = s; red[5 + wv] = sq; }

    {   // exact trig table
        float fk = (float)tid * (1.0f / 256.0f);
        tab[tid] = make_float2(cospif(fk), sinpif(fk));
        if (tid < 192) {
            float fk2 = (float)(tid + 320) * (1.0f / 256.0f);
            tab[tid + 320] = make_float2(cospif(fk2), sinpif(fk2));
        }
    }
    __syncthreads();

    if (tid < 256) {
        float a = zrow[tid], b = zrow[tid + 256];
        zeo[tid]       = a + b;   // for even p
        zeo[tid + 256] = a - b;   // for odd p
    }
    if (tid == 0) {
        float sum   = red[0]+red[1]+red[2]+red[3]+red[4];
        float sumsq = red[5]+red[6]+red[7]+red[8]+red[9];
        float mu  = sum * (1.0f / 512.0f);
        float var = sumsq * (1.0f / 512.0f) - mu * mu;
        float sg  = sqrtf(var + 1e-5f);
        int c = bc % CC;
        float w = aw[c], b = ab[c];
        *(float4*)(stats + 4 * bc) = make_float4(mu, sg, w / sg, b - w * mu / sg);
    }
    __syncthreads();

    if (tid < FREQ) {
        const int p = tid;
        const float* u = zeo + ((p & 1) ? 256 : 0);
        float ac = 0.f, as = 0.f;
        int k = 0;
#pragma unroll 8
        for (int t = 0; t < 256; ++t) {
            float uv = u[t];          // wave-uniform -> LDS broadcast
            float2 cs = tab[k];
            ac = fmaf(uv, cs.x, ac);
            as = fmaf(uv, cs.y, as);
            k = (k + p) & 511;
        }
        ZC[bc * FREQ + p] = ac;
        ZS[bc * FREQ + p] = as;
    }
}

// ---------------------------------------------------------------------------
// kB: THE streaming kernel (169 MB of head_w, read once, coalesced).
//   CA[p,l] = sum_t W[l,p,t] cos(2pi p t/T)   (x0.5 for p==0)
//   SA[p,l] = sum_t W[l,p,t] sin(2pi p t/T)
// One wave per (l,p): lanes cover t = 4*lane..4*lane+3, +256 chunk folds in
// with sign (-1)^p.  Native __sinf/__cosf base + 3 in-register rotations.
// grid = (65, 336) x 256 threads (4 waves; p = bx*4 + wave).
// ---------------------------------------------------------------------------
__global__ __launch_bounds__(256) void kB_wproj(const float* __restrict__ hw,
                                                float* __restrict__ CA,
                                                float* __restrict__ SA) {
    const int l    = blockIdx.y;
    const int w    = threadIdx.x >> 6;
    const int lane = threadIdx.x & 63;
    const int p    = blockIdx.x * 4 + w;
    if (p >= FREQ) return;

    const float4* src = (const float4*)(hw + (size_t)l * WROW + (size_t)p * TT);
    float4 w1 = src[lane];        // t = 4*lane .. 4*lane+3
    float4 w2 = src[lane + 64];   // t = 256 + 4*lane ..

    const float sgn = (p & 1) ? -1.0f : 1.0f;
    float u0 = fmaf(sgn, w2.x, w1.x);
    float u1 = fmaf(sgn, w2.y, w1.y);
    float u2 = fmaf(sgn, w2.z, w1.z);
    float u3 = fmaf(sgn, w2.w, w1.w);

    const int   k0 = (p * (lane * 4)) & 511;
    const float a0 = (float)k0 * ANG;
    float c0 = __cosf(a0), s0 = __sinf(a0);
    const float ad = (float)p * ANG;
    float cd = __cosf(ad), sd = __sinf(ad);

    float c1 = c0 * cd - s0 * sd, s1 = s0 * cd + c0 * sd;
    float c2 = c1 * cd - s1 * sd, s2 = s1 * cd + c1 * sd;
    float c3 = c2 * cd - s2 * sd, s3 = s2 * cd + c2 * sd;

    float accA = u0 * c0 + u1 * c1 + u2 * c2 + u3 * c3;
    float accB = u0 * s0 + u1 * s1 + u2 * s2 + u3 * s3;
    accA = wave_sum(accA);
    accB = wave_sum(accB);

    if (lane == 0) {
        if (p == 0) { accA *= 0.5f; accB *= 0.5f; }
        CA[p * LL + l] = accA;
        SA[p * LL + l] = accB;
    }
}

// ---------------------------------------------------------------------------
// kC: D[bc,l] = sum_p ZC[bc,p]*CA[p,l] + ZS[bc,p]*SA[p,l], fused epilogue:
//   pre = (2/T)*gamma*D + 2*delta*CA[0,l] + hb[l]
//   out = (pre - b)/(w + 1e-10) * sigma + mu
// Block = 4 bc-rows x 384 threads (l = tid).  CA/SA coalesced, ZC/ZS scalar.
// ---------------------------------------------------------------------------
__global__ __launch_bounds__(384) void kC_gemm(const float* __restrict__ ZC,
                                               const float* __restrict__ ZS,
                                               const float* __restrict__ CA,
                                               const float* __restrict__ SA,
                                               const float* __restrict__ stats,
                                               const float* __restrict__ aw,
                                               const float* __restrict__ ab,
                                               const float* __restrict__ hb,
                                               float* __restrict__ out) {
    const int l = threadIdx.x;
    if (l >= LL) return;
    const int bc0 = blockIdx.x * 4;
    const float* zc0 = ZC + (size_t)bc0 * FREQ;
    const float* zs0 = ZS + (size_t)bc0 * FREQ;

    float d0 = 0.f, d1 = 0.f, d2 = 0.f, d3 = 0.f;
#pragma unroll 4
    for (int p = 0; p < FREQ; ++p) {
        float ca = CA[p * LL + l];
        float sa = SA[p * LL + l];
        d0 = fmaf(zc0[p],            ca, fmaf(zs0[p],            sa, d0));
        d1 = fmaf(zc0[FREQ + p],     ca, fmaf(zs0[FREQ + p],     sa, d1));
        d2 = fmaf(zc0[2 * FREQ + p], ca, fmaf(zs0[2 * FREQ + p], sa, d2));
        d3 = fmaf(zc0[3 * FREQ + p], ca, fmaf(zs0[3 * FREQ + p], sa, d3));
    }
    const float ca0 = CA[l];      // CA[0, l] (already includes the 0.5)
    const float hbl = hb[l];
    float d[4] = {d0, d1, d2, d3};
#pragma unroll
    for (int j = 0; j < 4; ++j) {
        int bc = bc0 + j;
        int c  = bc % CC;
        float mu = stats[4 * bc + 0];
        float sg = stats[4 * bc + 1];
        float ga = stats[4 * bc + 2];
        float de = stats[4 * bc + 3];
        float pre = fmaf(ga * d[j], 2.0f / 512.0f, fmaf(2.0f * de, ca0, hbl));
        out[(size_t)bc * LL + l] = (pre - ab[c]) / (aw[c] + 1e-10f) * sg + mu;
    }
}

// ---------------------------------------------------------------------------
extern "C" void kernel_launch(void* const* d_in, const int* in_sizes, int n_in,
                              void* d_out, int out_size, void* d_ws, size_t ws_size,
                              hipStream_t stream) {
    const float* z  = (const float*)d_in[0];
    const float* aw = (const float*)d_in[1];
    const float* ab = (const float*)d_in[2];
    const float* hw = (const float*)d_in[3];
    const float* hb = (const float*)d_in[4];
    float* out = (float*)d_out;

    float* ws    = (float*)d_ws;
    float* ZC    = ws;                      // 672*257 = 172704
    float* ZS    = ZC + NBC * FREQ;         // 172704
    float* CA    = ZS + NBC * FREQ;         // 257*336 = 86352
    float* SA    = CA + FREQ * LL;          // 86352
    float* stats = SA + FREQ * LL;          // 672*4 (mu, sg, gamma, delta)
    // total ~2.1 MB of d_ws

    kB_wproj<<<dim3(65, 336), 256, 0, stream>>>(hw, CA, SA);
    kA_zdft <<<NBC, 320, 0, stream>>>(z, aw, ab, ZC, ZS, stats);
    kC_gemm <<<NBC / 4, 384, 0, stream>>>(ZC, ZS, CA, SA, stats, aw, ab, hb, out);
}

// Round 3
// 274.582 us; speedup vs baseline: 1.0970x; 1.0970x over previous
//
#include <hip/hip_runtime.h>
#include <math.h>

// Problem constants
#define BB 32
#define CC 21
#define TT 512
#define LL 336
#define FREQ 257            // TT/2 + 1
#define NBC (BB*CC)         // 672
#define WROW (FREQ*TT)      // 131584 floats per head_w row

#define ANG (6.2831853071795864769e0f / 512.0f)   // 2*pi/T

// Fused kernel-1 grid layout: first NBC blocks do the z-DFT (VALU-heavy,
// dispatched first so they hide under the head_w stream), remaining
// 52*336 blocks stream head_w (5 p-values per block, 5 waves of 320 thr).
#define PCHUNK 52           // ceil(257/5)
#define KB_BLOCKS (PCHUNK * LL)   // 17472

__device__ __forceinline__ float wave_sum(float v) {
#pragma unroll
    for (int off = 32; off; off >>= 1) v += __shfl_xor(v, off);
    return v;
}

// ---------------------------------------------------------------------------
// k1_fused:
//  role A (blockIdx.x < 672): per-(b,c) stats + DFT of raw z row.
//    ZC[bc,p] = sum_t z_t cos(2pi p t/T), ZS[bc,p] = sum_t z_t sin(...)
//    Even/odd fold halves t-loop; rotation recurrence in registers with an
//    exact-table rebase every 64 steps (drift <= ~6e-6 rad).
//  role B (else): CA[p,l] = sum_t W[l,p,t] cos(.), SA = sum_t W sin(.)
//    (x0.5 for p==0).  One wave per (l,p); 2x float4 coalesced loads/lane;
//    +256 fold with sign (-1)^p; 3 in-register rotations.
// ---------------------------------------------------------------------------
__global__ __launch_bounds__(320) void k1_fused(const float* __restrict__ z,
                                                const float* __restrict__ hw,
                                                const float* __restrict__ aw,
                                                const float* __restrict__ ab,
                                                float* __restrict__ ZC,
                                                float* __restrict__ ZS,
                                                float* __restrict__ CA,
                                                float* __restrict__ SA,
                                                float* __restrict__ stats) {
    const int tid  = threadIdx.x;
    const int lane = tid & 63;
    const int w    = tid >> 6;

    if (blockIdx.x >= NBC) {
        // ---------------- role B: head_w streaming ----------------
        const int bxx = blockIdx.x - NBC;
        const int l   = bxx / PCHUNK;
        const int pc  = bxx - l * PCHUNK;
        const int p   = pc * 5 + w;
        if (p >= FREQ) return;

        const float4* src = (const float4*)(hw + (size_t)l * WROW + (size_t)p * TT);
        float4 w1 = src[lane];        // t = 4*lane .. 4*lane+3
        float4 w2 = src[lane + 64];   // t = 256 + ...

        const float sgn = (p & 1) ? -1.0f : 1.0f;
        float u0 = fmaf(sgn, w2.x, w1.x);
        float u1 = fmaf(sgn, w2.y, w1.y);
        float u2 = fmaf(sgn, w2.z, w1.z);
        float u3 = fmaf(sgn, w2.w, w1.w);

        const int   k0 = (p * (lane * 4)) & 511;
        const float a0 = (float)k0 * ANG;
        float c0 = __cosf(a0), s0 = __sinf(a0);
        const float ad = (float)p * ANG;
        float cd = __cosf(ad), sd = __sinf(ad);

        float c1 = c0 * cd - s0 * sd, s1 = s0 * cd + c0 * sd;
        float c2 = c1 * cd - s1 * sd, s2 = s1 * cd + c1 * sd;
        float c3 = c2 * cd - s2 * sd, s3 = s2 * cd + c2 * sd;

        float accA = u0 * c0 + u1 * c1 + u2 * c2 + u3 * c3;
        float accB = u0 * s0 + u1 * s1 + u2 * s2 + u3 * s3;
        accA = wave_sum(accA);
        accB = wave_sum(accB);

        if (lane == 0) {
            if (p == 0) { accA *= 0.5f; accB *= 0.5f; }
            CA[p * LL + l] = accA;
            SA[p * LL + l] = accB;
        }
        return;
    }

    // ---------------- role A: z stats + DFT ----------------
    __shared__ float  zrow[512];
    __shared__ float  zeo[512];     // [0,256) even fold (a+b), [256,512) odd (a-b)
    __shared__ float2 tab[512];     // exact (cos,sin)(2*pi*k/512)
    __shared__ float  red[10];
    const int bc = blockIdx.x;
    const float* zr = z + (size_t)bc * TT;

    float v0 = zr[tid];
    float v1 = (tid < 192) ? zr[tid + 320] : 0.0f;
    zrow[tid] = v0;
    if (tid < 192) zrow[tid + 320] = v1;

    float s  = v0 + v1;
    float sq = v0 * v0 + v1 * v1;
    s  = wave_sum(s);
    sq = wave_sum(sq);
    if (lane == 0) { red[w] = s; red[5 + w] = sq; }

    {   // exact trig table (for chunk rebase)
        float fk = (float)tid * (1.0f / 256.0f);
        tab[tid] = make_float2(cospif(fk), sinpif(fk));
        if (tid < 192) {
            float fk2 = (float)(tid + 320) * (1.0f / 256.0f);
            tab[tid + 320] = make_float2(cospif(fk2), sinpif(fk2));
        }
    }
    __syncthreads();

    if (tid < 256) {
        float a = zrow[tid], b = zrow[tid + 256];
        zeo[tid]       = a + b;
        zeo[tid + 256] = a - b;
    }
    if (tid == 0) {
        float sum   = red[0]+red[1]+red[2]+red[3]+red[4];
        float sumsq = red[5]+red[6]+red[7]+red[8]+red[9];
        float mu  = sum * (1.0f / 512.0f);
        float var = sumsq * (1.0f / 512.0f) - mu * mu;
        float sg  = sqrtf(var + 1e-5f);
        int c = bc % CC;
        float ww = aw[c], bb = ab[c];
        *(float4*)(stats + 4 * bc) = make_float4(mu, sg, ww / sg, bb - ww * mu / sg);
    }
    __syncthreads();

    if (tid < FREQ) {
        const int p = tid;
        const float* u = zeo + ((p & 1) ? 256 : 0);
        const float ad = (float)p * ANG;
        const float cd = __cosf(ad), sd = __sinf(ad);
        float ac = 0.f, as_ = 0.f;
#pragma unroll
        for (int ch = 0; ch < 4; ++ch) {
            const int base = (p * (ch * 64)) & 511;
            float2 cs = tab[base];          // exact rebase
            float c = cs.x, sn = cs.y;
#pragma unroll 8
            for (int j = 0; j < 64; ++j) {
                float uv = u[ch * 64 + j];  // 2-address broadcast (free)
                ac  = fmaf(uv, c,  ac);
                as_ = fmaf(uv, sn, as_);
                float nc = fmaf(c, cd, -(sn * sd));
                sn = fmaf(sn, cd, c * sd);
                c  = nc;
            }
        }
        ZC[bc * FREQ + p] = ac;
        ZS[bc * FREQ + p] = as_;
    }
}

// ---------------------------------------------------------------------------
// kC: D[bc,l] = sum_p ZC*CA + ZS*SA, fused un-affine epilogue.
// Block = 2 bc-rows x 384 threads (l = tid) -> 336 blocks, all CUs busy.
// CA/SA coalesced (L2-resident, 690KB); ZC/ZS wave-uniform scalar loads.
//   pre = (2/T)*gamma*D + 2*delta*CA[0,l] + hb[l]
//   out = (pre - b)/(w + 1e-10) * sigma + mu
// ---------------------------------------------------------------------------
__global__ __launch_bounds__(384) void kC_gemm(const float* __restrict__ ZC,
                                               const float* __restrict__ ZS,
                                               const float* __restrict__ CA,
                                               const float* __restrict__ SA,
                                               const float* __restrict__ stats,
                                               const float* __restrict__ aw,
                                               const float* __restrict__ ab,
                                               const float* __restrict__ hb,
                                               float* __restrict__ out) {
    const int l = threadIdx.x;
    if (l >= LL) return;
    const int bc0 = blockIdx.x * 2;
    const float* zcA = ZC + (size_t)bc0 * FREQ;
    const float* zsA = ZS + (size_t)bc0 * FREQ;
    const float* zcB = zcA + FREQ;
    const float* zsB = zsA + FREQ;

    float d0 = 0.f, e0 = 0.f, d1 = 0.f, e1 = 0.f;   // 4 independent chains
#pragma unroll 8
    for (int p = 0; p < FREQ; ++p) {
        float ca = CA[p * LL + l];
        float sa = SA[p * LL + l];
        d0 = fmaf(zcA[p], ca, d0);
        e0 = fmaf(zsA[p], sa, e0);
        d1 = fmaf(zcB[p], ca, d1);
        e1 = fmaf(zsB[p], sa, e1);
    }
    const float ca0 = CA[l];      // CA[0,l] (includes the 0.5)
    const float hbl = hb[l];
    float d[2] = {d0 + e0, d1 + e1};
#pragma unroll
    for (int j = 0; j < 2; ++j) {
        int bc = bc0 + j;
        int c  = bc % CC;
        float mu = stats[4 * bc + 0];
        float sg = stats[4 * bc + 1];
        float ga = stats[4 * bc + 2];
        float de = stats[4 * bc + 3];
        float pre = fmaf(ga * d[j], 2.0f / 512.0f, fmaf(2.0f * de, ca0, hbl));
        out[(size_t)bc * LL + l] = (pre - ab[c]) / (aw[c] + 1e-10f) * sg + mu;
    }
}

// ---------------------------------------------------------------------------
extern "C" void kernel_launch(void* const* d_in, const int* in_sizes, int n_in,
                              void* d_out, int out_size, void* d_ws, size_t ws_size,
                              hipStream_t stream) {
    const float* z  = (const float*)d_in[0];
    const float* aw = (const float*)d_in[1];
    const float* ab = (const float*)d_in[2];
    const float* hw = (const float*)d_in[3];
    const float* hb = (const float*)d_in[4];
    float* out = (float*)d_out;

    float* ws    = (float*)d_ws;
    float* ZC    = ws;                      // 672*257
    float* ZS    = ZC + NBC * FREQ;
    float* CA    = ZS + NBC * FREQ;         // 257*336
    float* SA    = CA + FREQ * LL;
    float* stats = SA + FREQ * LL;          // 672*4 (mu, sg, gamma, delta)
    // total ~2.1 MB of d_ws

    k1_fused<<<NBC + KB_BLOCKS, 320, 0, stream>>>(z, hw, aw, ab, ZC, ZS, CA, SA, stats);
    kC_gemm <<<LL, 384, 0, stream>>>(ZC, ZS, CA, SA, stats, aw, ab, hb, out);
}